// Round 5
// baseline (120.262 us; speedup 1.0000x reference)
//
#include <hip/hip_runtime.h>
#include <hip/hip_bf16.h>
#include <stdint.h>
#include <stddef.h>

#define B_   8
#define N_   256
#define H_   128
#define E_   128
#define INZ  256
#define BIGN 1000000.0f

typedef float f32x4 __attribute__((ext_vector_type(4)));
typedef short bf16x8 __attribute__((ext_vector_type(8)));

static __device__ __forceinline__ unsigned cvt2(float a, float b) {
    unsigned short ra = __builtin_bit_cast(unsigned short, __float2bfloat16(a));
    unsigned short rb = __builtin_bit_cast(unsigned short, __float2bfloat16(b));
    return (unsigned)ra | ((unsigned)rb << 16);
}

static __device__ __forceinline__ bf16x8 mk_frag(f32x4 lo, f32x4 h4) {
    union { unsigned u[4]; bf16x8 v; } r;
    r.u[0] = cvt2(lo.x, lo.y);
    r.u[1] = cvt2(lo.z, lo.w);
    r.u[2] = cvt2(h4.x, h4.y);
    r.u[3] = cvt2(h4.z, h4.w);
    return r.v;
}

// ---------------------------------------------------------------------------
// prep: msg1 = z@W1+b1 ; m2g = z@W2+b2+graph@Wg+bg ; zo1 = z@Wo1+bo1
// blocks 0..7 also produce We^T -> bf16 LINEAR [e][k]
// 512 blocks x 256 threads, 4 rows/block
// ---------------------------------------------------------------------------
__global__ __launch_bounds__(256) void prep_kernel(
    const float* __restrict__ node, const float* __restrict__ hidden,
    const float* __restrict__ gf,
    const float* __restrict__ W1, const float* __restrict__ b1,
    const float* __restrict__ W2, const float* __restrict__ b2,
    const float* __restrict__ Wg, const float* __restrict__ bg,
    const float* __restrict__ Wo1, const float* __restrict__ bo1,
    const float* __restrict__ We,
    float* __restrict__ msg1, float* __restrict__ m2g,
    float* __restrict__ zo1, unsigned short* __restrict__ weT)
{
    __shared__ float zs[4][INZ];
    const int t  = threadIdx.x;
    const int r0 = blockIdx.x * 4;
    const int b  = r0 >> 8;

    for (int idx = t; idx < 4 * INZ; idx += 256) {
        int r = idx >> 8, k = idx & 255;
        int row = r0 + r;
        zs[r][k] = (k < H_) ? node[(size_t)row * H_ + k]
                            : hidden[(size_t)row * H_ + (k - H_)];
    }
    if (blockIdx.x < 8) {
        int e0 = blockIdx.x * 2048;
        for (int e = e0 + t; e < e0 + 2048; e += 256) {
            int n = e >> 7, k = e & 127;   // weT[e_col][k]
            weT[e] = (unsigned short)__builtin_bit_cast(unsigned short,
                         __float2bfloat16(We[k * 128 + n]));
        }
    }
    __syncthreads();

    const int col = t & 127;
    const int rg  = t >> 7;
    float a1[2] = {0, 0}, a2[2] = {0, 0}, ao[2] = {0, 0};

#pragma unroll 4
    for (int k = 0; k < INZ; ++k) {
        float w1 = W1[k * 128 + col];
        float w2 = W2[k * 128 + col];
        float wo = Wo1[k * 128 + col];
#pragma unroll
        for (int rr = 0; rr < 2; ++rr) {
            float zv = zs[rg * 2 + rr][k];
            a1[rr] = fmaf(zv, w1, a1[rr]);
            a2[rr] = fmaf(zv, w2, a2[rr]);
            ao[rr] = fmaf(zv, wo, ao[rr]);
        }
    }
    float mg = bg[col];
#pragma unroll 4
    for (int g = 0; g < 128; ++g)
        mg = fmaf(gf[b * 128 + g], Wg[g * 128 + col], mg);

    const float bb1 = b1[col], bb2 = b2[col], bbo = bo1[col];
#pragma unroll
    for (int rr = 0; rr < 2; ++rr) {
        size_t row = (size_t)(r0 + rg * 2 + rr);
        msg1[row * 128 + col] = a1[rr] + bb1;
        m2g[row * 128 + col]  = a2[rr] + bb2 + mg;
        zo1[row * 128 + col]  = ao[rr] + bbo;
    }
}

// ---------------------------------------------------------------------------
// main: 512 blocks = (b, ic 0..15, jq 0..3), 256 thr (4 waves).
// GEMM rows = j: wave w owns j-rows jq*64 + w*16 + 0..15, ALL 128 e-cols.
// Loop i over the block's 16-i chunk; rmax[j,e] persists in registers.
// A-frags load DIRECTLY global->VGPR (no LDS, no barriers); B (WeT) in
// 128 VGPRs loaded once. Per-i block footprint = 32KB contiguous.
// Partial max -> redp[blk][64 j][128 e].
// ---------------------------------------------------------------------------
__global__ __launch_bounds__(256, 2) void pgn_main(
    const float* __restrict__ edge, const float* __restrict__ adj,
    const float* __restrict__ m2g, const unsigned short* __restrict__ weT,
    float* __restrict__ redp)
{
    const int t    = threadIdx.x;
    const int lane = t & 63, wid = t >> 6;
    const int hi   = lane >> 4, c15 = lane & 15;
    const int blk  = blockIdx.x;
    const int b    = blk >> 6;
    const int ic   = (blk >> 2) & 15;
    const int jq   = blk & 3;
    const int i0   = ic * 16;
    const int jrow = jq * 64 + wid * 16 + c15;   // this lane's A row (j)

    // ---- B fragments: full WeT panel, 8 n x 4 ks = 128 VGPR ----
    bf16x8 bfr[8][4];
#pragma unroll
    for (int n = 0; n < 8; ++n) {
#pragma unroll
        for (int ks = 0; ks < 4; ++ks)
            bfr[n][ks] = *(const bf16x8*)(weT + (n * 16 + c15) * 128 + ks * 32 + hi * 8);
    }

    float rmax[8][4];
#pragma unroll
    for (int n = 0; n < 8; ++n)
#pragma unroll
        for (int rg = 0; rg < 4; ++rg) rmax[n][rg] = -BIGN;

    const float* abase = edge + ((size_t)(b * N_ + i0) * N_ + jrow) * E_ + hi * 8;
    const float* adjb  = adj + (size_t)(b * N_ + i0) * N_ + jq * 64 + wid * 16 + hi * 4;
    const float* m2gb  = m2g + (size_t)(b * N_ + i0) * 128 + c15;

#pragma unroll 2
    for (int ii = 0; ii < 16; ++ii) {
        const float* ar = abase + (size_t)ii * (N_ * E_);

        // mask + sender-term operands (L2-resident)
        f32x4 a4 = *(const f32x4*)(adjb + (size_t)ii * N_);
        float mv[8];
#pragma unroll
        for (int n = 0; n < 8; ++n) mv[n] = m2gb[(size_t)ii * 128 + n * 16];

        // ---- 16j x 128e x K=128: A direct from global, 32 MFMA ----
        f32x4 acc[8] = {};
#pragma unroll
        for (int ks = 0; ks < 4; ++ks) {
            f32x4 lo = *(const f32x4*)(ar + ks * 32);
            f32x4 h4 = *(const f32x4*)(ar + ks * 32 + 4);
            bf16x8 af = mk_frag(lo, h4);
#pragma unroll
            for (int n = 0; n < 8; ++n)
                acc[n] = __builtin_amdgcn_mfma_f32_16x16x32_bf16(
                    af, bfr[n][ks], acc[n], 0, 0, 0);
        }

        // ---- masked running max over i; C-row (=j) = hi*4+rg, col = n*16+c15
#pragma unroll
        for (int n = 0; n < 8; ++n)
#pragma unroll
            for (int rg = 0; rg < 4; ++rg) {
                float v = acc[n][rg] + mv[n];
                v = (a4[rg] > 0.0f) ? v : -BIGN;
                rmax[n][rg] = fmaxf(rmax[n][rg], v);
            }
    }

    // ---- write partial [64 j][128 e] for this block ----
    float* rp = redp + (size_t)blk * 8192;
#pragma unroll
    for (int n = 0; n < 8; ++n)
#pragma unroll
        for (int rg = 0; rg < 4; ++rg) {
            int jl = wid * 16 + hi * 4 + rg;
            rp[jl * 128 + n * 16 + c15] = rmax[n][rg];
        }
}

// ---------------------------------------------------------------------------
// finish: red = max over 16 i-chunks; out = relu(zo1 + (red+msg1+be)@Wo2+bo2)
// 256 blocks x 256 threads, 8 rows/block
// ---------------------------------------------------------------------------
__global__ __launch_bounds__(256) void finish_kernel(
    const float* __restrict__ redp, const float* __restrict__ msg1,
    const float* __restrict__ zo1, const float* __restrict__ be,
    const float* __restrict__ Wo2, const float* __restrict__ bo2,
    float* __restrict__ out)
{
    __shared__ float rb[8][128];
    const int t  = threadIdx.x;
    const int r0 = blockIdx.x * 8;

    for (int idx = t; idx < 1024; idx += 256) {
        int rr = idx >> 7, k = idx & 127;
        int r  = r0 + rr;
        int b  = r >> 8, j = r & 255;
        int jq = j >> 6, jl = j & 63;
        float v = -BIGN - 1.0f;
#pragma unroll 4
        for (int ic = 0; ic < 16; ++ic)
            v = fmaxf(v, redp[(size_t)(((b * 16 + ic) * 4) + jq) * 8192 + jl * 128 + k]);
        rb[rr][k] = v + msg1[(size_t)r * 128 + k] + be[k];
    }
    __syncthreads();

    const int col  = t & 127;
    const int half = t >> 7;
#pragma unroll
    for (int rx = 0; rx < 4; ++rx) {
        int rr = half * 4 + rx;
        size_t row = (size_t)(r0 + rr);
        float a = 0.0f;
#pragma unroll 8
        for (int k = 0; k < 128; ++k)
            a = fmaf(rb[rr][k], Wo2[k * 128 + col], a);
        float o = zo1[row * 128 + col] + bo2[col] + a;
        out[row * 128 + col] = fmaxf(o, 0.0f);
    }
}

extern "C" void kernel_launch(void* const* d_in, const int* in_sizes, int n_in,
                              void* d_out, int out_size, void* d_ws, size_t ws_size,
                              hipStream_t stream) {
    const float* node   = (const float*)d_in[0];
    const float* edge   = (const float*)d_in[1];
    const float* gf     = (const float*)d_in[2];
    const float* adj    = (const float*)d_in[3];
    const float* hidden = (const float*)d_in[4];
    const float* W1  = (const float*)d_in[5];
    const float* b1  = (const float*)d_in[6];
    const float* W2  = (const float*)d_in[7];
    const float* b2  = (const float*)d_in[8];
    const float* We  = (const float*)d_in[9];
    const float* be  = (const float*)d_in[10];
    const float* Wg  = (const float*)d_in[11];
    const float* bg  = (const float*)d_in[12];
    const float* Wo1 = (const float*)d_in[13];
    const float* bo1 = (const float*)d_in[14];
    const float* Wo2 = (const float*)d_in[15];
    const float* bo2 = (const float*)d_in[16];
    float* out = (float*)d_out;

    float* msg1 = (float*)d_ws;                                   // 1 MB
    float* m2g  = msg1 + 2048 * 128;                              // 1 MB
    float* zo1  = m2g + 2048 * 128;                               // 1 MB
    unsigned short* weT = (unsigned short*)(zo1 + 2048 * 128);    // 32 KB
    float* redp = (float*)((char*)weT + 128 * 128 * sizeof(unsigned short)); // 16 MB

    hipLaunchKernelGGL(prep_kernel, dim3(512), dim3(256), 0, stream,
                       node, hidden, gf, W1, b1, W2, b2, Wg, bg, Wo1, bo1, We,
                       msg1, m2g, zo1, weT);
    hipLaunchKernelGGL(pgn_main, dim3(512), dim3(256), 0, stream,
                       edge, adj, m2g, weT, redp);
    hipLaunchKernelGGL(finish_kernel, dim3(256), dim3(256), 0, stream,
                       redp, msg1, zo1, be, Wo2, bo2, out);
}